// Round 3
// baseline (188.593 us; speedup 1.0000x reference)
//
#include <hip/hip_runtime.h>
#include <hip/hip_bf16.h>

// Problem constants (fixed by the reference file).
#define BB 16
#define HH 512
#define WW 512
#define PIX_PER_THREAD 4          // 4 px * 9 fp32 = 144 B = 9 aligned float4 stores
#define THREADS_PER_BATCH ((HH * WW) / PIX_PER_THREAD)   // 65536
#define TOTAL_THREADS (BB * THREADS_PER_BATCH)           // 1048576
#define BLOCK 256

__global__ __launch_bounds__(BLOCK) void jac_kernel(
    const float* __restrict__ roll,
    const float* __restrict__ pitch,
    const float* __restrict__ focal,
    float* __restrict__ out)
{
    const int t = blockIdx.x * BLOCK + threadIdx.x;
    const int b = t >> 16;                         // t / THREADS_PER_BATCH
    const int pix0 = (t & (THREADS_PER_BATCH - 1)) * PIX_PER_THREAD;
    const int y  = pix0 >> 9;                      // / WW
    const int x0 = pix0 & (WW - 1);                // 0..508, never crosses a row

    // ---- per-batch constants (wave-uniform -> scalarized by compiler) ----
    const float rl = roll[b];
    const float pt = pitch[b];
    const float f  = focal[b];
    const float sr = sinf(rl), cr = cosf(rl);
    const float sp = sinf(pt), cp = cosf(pt);
    const float a0 = -sr * cp, a1 = -cr * cp, a2 = -sp;   // abc
    // J_rp (3x2): row0=(-cr*cp, sr*sp) row1=(sr*cp, cr*sp) row2=(0, -cp)
    const float J00 = -cr * cp, J01 = sr * sp;
    const float J10 =  sr * cp, J11 = cr * sp;
    const float J21 = -cp;                                 // J20 == 0
    const float invf = 1.0f / f;

    const float u1 = ((float)y + 0.5f - (float)HH * 0.5f) * invf;
    const float c3 = a2;

    // Pack 4 pixels * 9 fp32 = 144 B into registers, then 9 x 16B stores.
    union { float h[PIX_PER_THREAD * 9]; float4 v[9]; } ubuf;

#pragma unroll
    for (int p = 0; p < PIX_PER_THREAD; ++p) {
        const float u0 = ((float)(x0 + p) + 0.5f - (float)WW * 0.5f) * invf;

        // proj = abc[:2] - c3*uv
        const float p0 = a0 - c3 * u0;
        const float p1 = a1 - c3 * u1;

        // J_norm2proj (2x2 symmetric): I/n - vvT/n^3
        const float n2     = p0 * p0 + p1 * p1;
        const float inv_n  = rsqrtf(n2);
        const float inv_n3 = inv_n * inv_n * inv_n;
        const float M00 = inv_n - p0 * p0 * inv_n3;
        const float M01 =        -p0 * p1 * inv_n3;
        const float M11 = inv_n - p1 * p1 * inv_n3;

        // J_proj2delta = [[1,0,-u0],[0,1,-u1]] @ J_rp   (J20 = 0)
        const float P00 = J00;
        const float P01 = J01 + u0 * cp;   // J01 - u0*J21
        const float P10 = J10;
        const float P11 = J11 + u1 * cp;

        // J_up2delta = M @ P
        const float A00 = M00 * P00 + M01 * P10;
        const float A01 = M00 * P01 + M01 * P11;
        const float A10 = M01 * P00 + M11 * P10;
        const float A11 = M01 * P01 + M11 * P11;

        // J_proj2f = c3*uv/f ;  J_up2f = M @ J_proj2f
        const float q0 = c3 * u0 * invf;
        const float q1 = c3 * u1 * invf;
        const float A02 = M00 * q0 + M01 * q1;
        const float A12 = M01 * q0 + M11 * q1;

        // uv1 = (u0,u1,1); its vecnorm jacobian pieces
        const float nn2     = u0 * u0 + u1 * u1 + 1.0f;
        const float inv_nn  = rsqrtf(nn2);
        const float inv_nn3 = inv_nn * inv_nn * inv_nn;

        // J_delta = uv1_norm @ J_rp   (J20 = 0)
        const float D0 = inv_nn * (u0 * J00 + u1 * J10);
        const float D1 = inv_nn * (u0 * J01 + u1 * J11 + J21);

        // J_norm2f = J_norm2img @ (-uv/f);  J_f = J_norm2f . abc
        const float w0 = -u0 * invf;
        const float w1 = -u1 * invf;
        const float s  = u0 * w0 + u1 * w1;
        const float g0 = inv_nn * w0 - u0 * inv_nn3 * s;
        const float g1 = inv_nn * w1 - u1 * inv_nn3 * s;
        const float g2 =             -      inv_nn3 * s;
        const float F  = g0 * a0 + g1 * a1 + g2 * a2;

        ubuf.h[p * 9 + 0] = A00;
        ubuf.h[p * 9 + 1] = A01;
        ubuf.h[p * 9 + 2] = A02;
        ubuf.h[p * 9 + 3] = A10;
        ubuf.h[p * 9 + 4] = A11;
        ubuf.h[p * 9 + 5] = A12;
        ubuf.h[p * 9 + 6] = D0;
        ubuf.h[p * 9 + 7] = D1;
        ubuf.h[p * 9 + 8] = F;
    }

    // 144-byte contiguous block per thread, 16B-aligned (t*144 % 16 == 0).
    float4* __restrict__ ov = (float4*)(out + (size_t)t * (PIX_PER_THREAD * 9));
#pragma unroll
    for (int k = 0; k < 9; ++k) ov[k] = ubuf.v[k];
}

extern "C" void kernel_launch(void* const* d_in, const int* in_sizes, int n_in,
                              void* d_out, int out_size, void* d_ws, size_t ws_size,
                              hipStream_t stream) {
    const float* roll  = (const float*)d_in[0];
    const float* pitch = (const float*)d_in[1];
    const float* focal = (const float*)d_in[2];
    float* out = (float*)d_out;

    dim3 grid(TOTAL_THREADS / BLOCK);   // 4096
    dim3 block(BLOCK);
    jac_kernel<<<grid, block, 0, stream>>>(roll, pitch, focal, out);
}

// Round 4
// 159.680 us; speedup vs baseline: 1.1811x; 1.1811x over previous
//
#include <hip/hip_runtime.h>
#include <hip/hip_bf16.h>

// Problem constants (fixed by the reference file).
#define BB 16
#define HH 512
#define WW 512
#define PIX_PER_THREAD 4          // 4 px * 9 fp32 = 144 B = 9 float4s per thread
#define THREADS_PER_BATCH ((HH * WW) / PIX_PER_THREAD)   // 65536
#define TOTAL_THREADS (BB * THREADS_PER_BATCH)           // 1048576
#define BLOCK 256
#define F4_PER_THREAD 9           // 9 float4 = 144 B
#define F4_PER_BLOCK (BLOCK * F4_PER_THREAD)             // 2304 float4 = 36864 B

__global__ __launch_bounds__(BLOCK) void jac_kernel(
    const float* __restrict__ roll,
    const float* __restrict__ pitch,
    const float* __restrict__ focal,
    float* __restrict__ out)
{
    // LDS staging for fully-coalesced global stores.
    // Slot stride per thread = 9 float4 = 36 words; 36 = 4*9, 9 odd ->
    // b128 write phases spread over all 32 banks (8 bank-cycles = floor).
    __shared__ float4 lds4[F4_PER_BLOCK];

    const int t = blockIdx.x * BLOCK + threadIdx.x;
    const int b = t >> 16;                         // t / THREADS_PER_BATCH
    const int pix0 = (t & (THREADS_PER_BATCH - 1)) * PIX_PER_THREAD;
    const int y  = pix0 >> 9;                      // / WW
    const int x0 = pix0 & (WW - 1);                // 0..508, never crosses a row

    // ---- per-batch constants (wave-uniform -> scalarized by compiler) ----
    const float rl = roll[b];
    const float pt = pitch[b];
    const float f  = focal[b];
    const float sr = sinf(rl), cr = cosf(rl);
    const float sp = sinf(pt), cp = cosf(pt);
    const float a0 = -sr * cp, a1 = -cr * cp, a2 = -sp;   // abc
    // J_rp (3x2): row0=(-cr*cp, sr*sp) row1=(sr*cp, cr*sp) row2=(0, -cp)
    const float J00 = -cr * cp, J01 = sr * sp;
    const float J10 =  sr * cp, J11 = cr * sp;
    const float J21 = -cp;                                 // J20 == 0
    const float invf = 1.0f / f;

    const float u1 = ((float)y + 0.5f - (float)HH * 0.5f) * invf;
    const float c3 = a2;

    union { float h[PIX_PER_THREAD * 9]; float4 v[F4_PER_THREAD]; } ubuf;

#pragma unroll
    for (int p = 0; p < PIX_PER_THREAD; ++p) {
        const float u0 = ((float)(x0 + p) + 0.5f - (float)WW * 0.5f) * invf;

        // proj = abc[:2] - c3*uv
        const float p0 = a0 - c3 * u0;
        const float p1 = a1 - c3 * u1;

        // J_norm2proj (2x2 symmetric): I/n - vvT/n^3
        const float n2     = p0 * p0 + p1 * p1;
        const float inv_n  = rsqrtf(n2);
        const float inv_n3 = inv_n * inv_n * inv_n;
        const float M00 = inv_n - p0 * p0 * inv_n3;
        const float M01 =        -p0 * p1 * inv_n3;
        const float M11 = inv_n - p1 * p1 * inv_n3;

        // J_proj2delta = [[1,0,-u0],[0,1,-u1]] @ J_rp   (J20 = 0)
        const float P00 = J00;
        const float P01 = J01 + u0 * cp;   // J01 - u0*J21
        const float P10 = J10;
        const float P11 = J11 + u1 * cp;

        // J_up2delta = M @ P
        const float A00 = M00 * P00 + M01 * P10;
        const float A01 = M00 * P01 + M01 * P11;
        const float A10 = M01 * P00 + M11 * P10;
        const float A11 = M01 * P01 + M11 * P11;

        // J_proj2f = c3*uv/f ;  J_up2f = M @ J_proj2f
        const float q0 = c3 * u0 * invf;
        const float q1 = c3 * u1 * invf;
        const float A02 = M00 * q0 + M01 * q1;
        const float A12 = M01 * q0 + M11 * q1;

        // uv1 = (u0,u1,1); its vecnorm jacobian pieces
        const float nn2     = u0 * u0 + u1 * u1 + 1.0f;
        const float inv_nn  = rsqrtf(nn2);
        const float inv_nn3 = inv_nn * inv_nn * inv_nn;

        // J_delta = uv1_norm @ J_rp   (J20 = 0)
        const float D0 = inv_nn * (u0 * J00 + u1 * J10);
        const float D1 = inv_nn * (u0 * J01 + u1 * J11 + J21);

        // J_norm2f = J_norm2img @ (-uv/f);  J_f = J_norm2f . abc
        const float w0 = -u0 * invf;
        const float w1 = -u1 * invf;
        const float s  = u0 * w0 + u1 * w1;
        const float g0 = inv_nn * w0 - u0 * inv_nn3 * s;
        const float g1 = inv_nn * w1 - u1 * inv_nn3 * s;
        const float g2 =             -      inv_nn3 * s;
        const float F  = g0 * a0 + g1 * a1 + g2 * a2;

        ubuf.h[p * 9 + 0] = A00;
        ubuf.h[p * 9 + 1] = A01;
        ubuf.h[p * 9 + 2] = A02;
        ubuf.h[p * 9 + 3] = A10;
        ubuf.h[p * 9 + 4] = A11;
        ubuf.h[p * 9 + 5] = A12;
        ubuf.h[p * 9 + 6] = D0;
        ubuf.h[p * 9 + 7] = D1;
        ubuf.h[p * 9 + 8] = F;
    }

    // Phase 1: registers -> LDS (AoS order, stride 36 words -> no net conflict)
#pragma unroll
    for (int k = 0; k < F4_PER_THREAD; ++k)
        lds4[threadIdx.x * F4_PER_THREAD + k] = ubuf.v[k];

    __syncthreads();

    // Phase 2: LDS -> global, block-linear => lane-contiguous float4 stores.
    float4* __restrict__ ob = (float4*)out + (size_t)blockIdx.x * F4_PER_BLOCK;
#pragma unroll
    for (int k = 0; k < F4_PER_THREAD; ++k) {
        const int idx = k * BLOCK + threadIdx.x;
        ob[idx] = lds4[idx];
    }
}

extern "C" void kernel_launch(void* const* d_in, const int* in_sizes, int n_in,
                              void* d_out, int out_size, void* d_ws, size_t ws_size,
                              hipStream_t stream) {
    const float* roll  = (const float*)d_in[0];
    const float* pitch = (const float*)d_in[1];
    const float* focal = (const float*)d_in[2];
    float* out = (float*)d_out;

    dim3 grid(TOTAL_THREADS / BLOCK);   // 4096
    dim3 block(BLOCK);
    jac_kernel<<<grid, block, 0, stream>>>(roll, pitch, focal, out);
}